// Round 8
// baseline (364.574 us; speedup 1.0000x reference)
//
#include <hip/hip_runtime.h>

constexpr int kN = 4096;
constexpr int kDim = 66;   // U + IN
constexpr int kU = 64;
constexpr float kAlpha = 0.2f;
constexpr float kSlope = 0.01f;
constexpr float kLog2e = 1.44269504f;

typedef _Float16 half8 __attribute__((ext_vector_type(8)));
typedef _Float16 half2t __attribute__((ext_vector_type(2)));
typedef float floatx4 __attribute__((ext_vector_type(4)));

__device__ inline unsigned int fkey(float f){ // monotone float->uint key for atomicMax
  unsigned int u = __float_as_uint(f);
  return (u & 0x80000000u) ? ~u : (u | 0x80000000u);
}
__device__ inline float funkey(unsigned int k){
  unsigned int u = (k & 0x80000000u) ? (k ^ 0x80000000u) : ~k;
  return __uint_as_float(u);
}

// ---------- merged setup: pack adjacency + build fp16 x1/x2 + all B matrices + fmax init ----------
__global__ void setup_k(const int* __restrict__ adj, unsigned long long* __restrict__ packed,
                        const float* __restrict__ in2, const float* __restrict__ hx,
                        _Float16* __restrict__ x1b, _Float16* __restrict__ x2b,
                        const float* __restrict__ m1W, const float* __restrict__ m1a1, const float* __restrict__ m1a2,
                        const float* __restrict__ m1Wo, const float* __restrict__ m1ao1, const float* __restrict__ m1ao2,
                        const float* __restrict__ m2W, const float* __restrict__ m2a1, const float* __restrict__ m2a2,
                        const float* __restrict__ m2Wo, const float* __restrict__ m2ao1, const float* __restrict__ m2ao2,
                        const float* __restrict__ g1W, const float* __restrict__ g1b,
                        const float* __restrict__ g2W, const float* __restrict__ g2b,
                        _Float16* __restrict__ B1t, _Float16* __restrict__ B1t2,
                        _Float16* __restrict__ B2t, _Float16* __restrict__ B2t2,
                        _Float16* __restrict__ Bgt, _Float16* __restrict__ Bft,
                        unsigned int* __restrict__ fmaxbuf){
  int bb = blockIdx.x, t = threadIdx.x;
  if (bb < 16384){
    int gid = bb * 256 + t;
    unsigned long long m = __ballot(adj[gid] != 0);
    if ((t & 63) == 0) packed[gid >> 6] = m;
    return;
  }
  if (bb < 16384 + 1024){
    int i = (bb - 16384) * 4 + (t >> 6);
    int c = t & 63;
    x1b[(size_t)i * 96 + 2 + c] = (_Float16)hx[(size_t)i * kU + c];
    if (c < 2){
      _Float16 xv = (_Float16)in2[i * 2 + c];
      x1b[(size_t)i * 96 + c] = xv;
      x2b[(size_t)i * 96 + c] = xv;
    }
    if (c < 30){ // zero pad cols 66..95 (ws is poisoned)
      x1b[(size_t)i * 96 + 66 + c] = (_Float16)0.f;
      x2b[(size_t)i * 96 + 66 + c] = (_Float16)0.f;
    }
    return;
  }
  int b = bb - (16384 + 1024);
  if (b < 8){
    int m = b & 3;
    const float* W  = (b < 4 ? m1W  : m2W)  + (size_t)m * kDim * kDim;
    const float* a1 = (b < 4 ? m1a1 : m2a1) + m * kDim;
    const float* a2 = (b < 4 ? m1a2 : m2a2) + m * kDim;
    _Float16* Bo = (b < 4 ? B1t : B1t2) + (size_t)m * 80 * 96;
    __shared__ float Ws[kDim * kDim];
    __shared__ float wa1s[kDim], wa2s[kDim];
    for (int z = t; z < kDim * kDim; z += 256) Ws[z] = W[z];
    __syncthreads();
    if (t < kDim){
      float s1 = 0.f, s2 = 0.f;
      for (int d = 0; d < kDim; d++){ float wv = Ws[t * kDim + d]; s1 += wv * a1[d]; s2 += wv * a2[d]; }
      wa1s[t] = s1; wa2s[t] = s2;
    }
    __syncthreads();
    for (int z = t; z < 80 * 96; z += 256){
      int nn = z / 96, k = z % 96;
      float val = 0.f;
      if (k < kDim){
        if (nn < kDim) val = Ws[k * kDim + nn];
        else if (nn == 66) val = wa1s[k];
        else if (nn == 67) val = wa2s[k];
      }
      Bo[z] = (_Float16)val;
    }
  } else if (b < 10){
    const float* Wo  = (b == 8 ? m1Wo  : m2Wo);
    const float* ao1 = (b == 8 ? m1ao1 : m2ao1);
    const float* ao2 = (b == 8 ? m1ao2 : m2ao2);
    _Float16* Bo = (b == 8 ? B2t : B2t2);
    __shared__ float wo1s[264], wo2s[264];
    for (int k = t; k < 264; k += 256){
      float s1 = 0.f, s2 = 0.f;
      for (int d = 0; d < kDim; d++){ float wv = Wo[(size_t)k * kDim + d]; s1 += wv * ao1[d]; s2 += wv * ao2[d]; }
      wo1s[k] = s1; wo2s[k] = s2;
    }
    __syncthreads();
    for (int z = t; z < 80 * 288; z += 256){
      int nn = z / 288, k = z % 288;
      float val = 0.f;
      if (k < 264){
        if (nn < kDim) val = Wo[(size_t)k * kDim + nn];
        else if (nn == 66) val = wo1s[k];
        else if (nn == 67) val = wo2s[k];
      }
      Bo[z] = (_Float16)val;
    }
  } else if (b == 10){
    for (int z = t; z < 128 * 96; z += 256){
      int nn = z / 96, k = z % 96;
      float val = 0.f;
      if (k < kDim) val = g1W[k * 128 + nn];
      else if (k == 66) val = g1b[nn];
      Bgt[z] = (_Float16)val;
    }
  } else {
    if (t < 16) fmaxbuf[t] = 0u;
    for (int z = t; z < 64 * 96; z += 256){
      int nn = z / 96, k = z % 96;
      float val = 0.f;
      if (k < kDim) val = g2W[k * 64 + nn];
      else if (k == 66) val = g2b[nn];
      Bft[z] = (_Float16)val;
    }
  }
}

// ---- generic MFMA GEMM core ----
template<int KSTEPS, int NT>
__device__ __forceinline__ void gemmN(const _Float16* __restrict__ Arow,
                                      const _Float16* __restrict__ Bt, floatx4* acc){
  const int lane = threadIdx.x & 63, q = lane >> 4, n = lane & 15;
  #pragma unroll
  for (int v = 0; v < NT; v++) acc[v] = (floatx4){0.f, 0.f, 0.f, 0.f};
  #pragma unroll
  for (int ks = 0; ks < KSTEPS; ks++){
    half8 af = *(const half8*)&Arow[ks * 32 + q * 8];
    #pragma unroll
    for (int nt = 0; nt < NT; nt++){
      half8 bf = *(const half8*)&Bt[(size_t)(nt * 16 + n) * (KSTEPS * 32) + ks * 32 + q * 8];
      acc[nt] = __builtin_amdgcn_mfma_f32_16x16x32_f16(af, bf, acc[nt], 0, 0, 0);
    }
  }
}

// ---- EPI0: store Ht (fp16 transposed + ones row 66 + zero row 67), f1/f2 (xlog2e), fmax ----
__device__ __forceinline__ void epi0(floatx4* acc, int i0, _Float16* __restrict__ Htc,
                                     float* __restrict__ f1c, float* __restrict__ f2c,
                                     unsigned* __restrict__ fmaxslot){
  const int t = threadIdx.x, w = t >> 6, lane = t & 63, q = lane >> 4, n = lane & 15;
  const int ib = i0 + w * 16 + q * 4;
  float lm = -3e38f;
  #pragma unroll
  for (int nt = 0; nt < 5; nt++){
    int c = nt * 16 + n;
    if (c < kDim){
      union { _Float16 h[4]; uint2 v; } pk;
      pk.h[0] = (_Float16)acc[nt][0]; pk.h[1] = (_Float16)acc[nt][1];
      pk.h[2] = (_Float16)acc[nt][2]; pk.h[3] = (_Float16)acc[nt][3];
      *(uint2*)&Htc[(size_t)c * kN + ib] = pk.v;
    } else if (c == 66){
      float4 fv; fv.x = acc[nt][0] * kLog2e; fv.y = acc[nt][1] * kLog2e;
      fv.z = acc[nt][2] * kLog2e; fv.w = acc[nt][3] * kLog2e;
      *(float4*)&f1c[ib] = fv;
      *(uint2*)&Htc[(size_t)66 * kN + ib] = make_uint2(0x3C003C00u, 0x3C003C00u);
    } else if (c == 67){
      float4 fv; fv.x = acc[nt][0] * kLog2e; fv.y = acc[nt][1] * kLog2e;
      fv.z = acc[nt][2] * kLog2e; fv.w = acc[nt][3] * kLog2e;
      *(float4*)&f2c[ib] = fv;
      lm = fmaxf(fmaxf(fv.x, fv.y), fmaxf(fv.z, fv.w));
      *(uint2*)&Htc[(size_t)67 * kN + ib] = make_uint2(0u, 0u);
    }
  }
  lm = fmaxf(lm, __shfl_xor(lm, 16));
  lm = fmaxf(lm, __shfl_xor(lm, 32));
  if (lane == 3) atomicMax(fmaxslot, fkey(lm));
}

// ---------- head transform GEMM ----------
__global__ __launch_bounds__(256) void gemm_ht_k(
    const _Float16* __restrict__ A, const _Float16* __restrict__ Bt,
    _Float16* __restrict__ Ht, float* __restrict__ f1, float* __restrict__ f2,
    unsigned int* __restrict__ fmaxp)
{
  const int m = blockIdx.y;
  const int i0 = blockIdx.x * 64;
  const int w = threadIdx.x >> 6, n = threadIdx.x & 15;
  floatx4 acc[5];
  gemmN<3, 5>(A + (size_t)(i0 + w * 16 + n) * 96, Bt + (size_t)m * 80 * 96, acc);
  epi0(acc, i0, Ht + (size_t)m * 80 * kN, f1 + (size_t)m * kN, f2 + (size_t)m * kN, fmaxp + m);
}

// ---------- barrier-free MFMA attention: M = TPW*16 rows per wave, direct-global B-frags ----------
// All 4 waves of a block share one j-window (jbase = z*KSR*32) -> 4x L1 reuse of H lines.
// slice = blockIdx.y * gridDim.z + blockIdx.z; pacc stride 72.
template<int TPW, int KSR>
__global__ __launch_bounds__(256, 2) void attn_mfma_k(
    const _Float16* __restrict__ Ht, const float* __restrict__ f1,
    const float* __restrict__ f2, const unsigned int* __restrict__ fmaxu,
    const unsigned long long* __restrict__ packed,
    _Float16* __restrict__ paccb)
{
  constexpr int WJ = KSR * 32;             // j-window per block
  const int m = blockIdx.y;
  const int t = threadIdx.x;
  const int w = t >> 6, lane = t & 63, q = lane >> 4, n = lane & 15;
  const int i0b = blockIdx.x * (TPW * 64);
  const int wrb = i0b + w * (TPW * 16);     // wave row base
  const int jbase = blockIdx.z * WJ;
  const _Float16* Hg = Ht + (size_t)m * 80 * kN;
  const float* f2m = f2 + (size_t)m * kN;
  const float* f1m = f1 + (size_t)m * kN;
  const float fmx = funkey(fmaxu[m]);

  __shared__ __align__(16) _Float16 B1h[WJ], B2h[WJ];
  for (int z = t; z < WJ; z += 256){
    float v = f2m[jbase + z] - fmx;
    B1h[z] = (_Float16)__builtin_amdgcn_exp2f(v);
    B2h[z] = (_Float16)__builtin_amdgcn_exp2f(kAlpha * v);
  }
  __syncthreads();

  half2t a1p[TPW], a2p[TPW];
  const unsigned long long* prow[TPW];
  #pragma unroll
  for (int a = 0; a < TPW; a++){
    int i = wrb + a * 16 + n;
    float t0 = f1m[i] + fmx;
    float S = fmaxf(t0, kAlpha * t0);
    _Float16 A1 = (_Float16)__builtin_amdgcn_exp2f(t0 - S);
    _Float16 A2 = (_Float16)__builtin_amdgcn_exp2f(kAlpha * t0 - S);
    a1p[a] = (half2t){A1, A1};
    a2p[a] = (half2t){A2, A2};
    prow[a] = packed + (size_t)i * 64;
  }

  floatx4 acc[TPW][5];
  #pragma unroll
  for (int a = 0; a < TPW; a++)
    #pragma unroll
    for (int v = 0; v < 5; v++) acc[a][v] = (floatx4){0.f, 0.f, 0.f, 0.f};

  unsigned long long mw[TPW];
  #pragma unroll
  for (int ks = 0; ks < KSR; ks++){
    if ((ks & 1) == 0){
      int widx = (jbase >> 6) + (ks >> 1);
      #pragma unroll
      for (int a = 0; a < TPW; a++) mw[a] = prow[a][widx];
    }
    const unsigned shift = (ks & 1) * 32 + q * 8;
    const int jo = ks * 32 + q * 8;
    union { uint4 v; unsigned u[4]; } b1v, b2v;
    b1v.v = *(const uint4*)&B1h[jo];
    b2v.v = *(const uint4*)&B2h[jo];
    union { half8 s; unsigned u[4]; } af[TPW];
    #pragma unroll
    for (int a = 0; a < TPW; a++){
      unsigned bits = (unsigned)((mw[a] >> shift) & 0xffull);
      #pragma unroll
      for (int e = 0; e < 4; e++){
        half2t x1 = __builtin_bit_cast(half2t, b1v.u[e]);
        half2t x2 = __builtin_bit_cast(half2t, b2v.u[e]);
        half2t pm = __builtin_elementwise_max(x1 * a1p[a], x2 * a2p[a]);
        unsigned mmk = (((bits >> (2 * e)) & 1u) ? 0x0000FFFFu : 0u)
                     | (((bits >> (2 * e + 1)) & 1u) ? 0xFFFF0000u : 0u);
        af[a].u[e] = __builtin_bit_cast(unsigned, pm) & mmk;
      }
    }
    const _Float16* hb = Hg + jbase + jo;
    #pragma unroll
    for (int nt = 0; nt < 5; nt++){
      half8 bf = *(const half8*)&hb[(size_t)(nt * 16 + n) * kN];
      #pragma unroll
      for (int a = 0; a < TPW; a++)
        acc[a][nt] = __builtin_amdgcn_mfma_f32_16x16x32_f16(af[a].s, bf, acc[a][nt], 0, 0, 0);
    }
  }
  const int slice = blockIdx.y * gridDim.z + blockIdx.z;
  _Float16* pw = paccb + ((size_t)slice * kN + wrb) * 72;
  #pragma unroll
  for (int a = 0; a < TPW; a++){
    #pragma unroll
    for (int nt = 0; nt < 5; nt++){
      if (nt < 4 || n < 4){ // cols >= 68 unused
        #pragma unroll
        for (int r = 0; r < 4; r++)
          pw[(a * 16 + q * 4 + r) * 72 + nt * 16 + n] = (_Float16)acc[a][nt][r];
      }
    }
  }
}

// ---------- fused: combine 8-split x 4-head partials -> LDS hcat -> out GEMM (K=288) -> epi0 ----------
__global__ __launch_bounds__(256) void combineH_gemmO_k(
    const _Float16* __restrict__ pacc, const _Float16* __restrict__ B2tc,
    _Float16* __restrict__ Htoc, float* __restrict__ fo1c, float* __restrict__ fo2c,
    unsigned int* __restrict__ fmaxslot)
{
  __shared__ __align__(16) _Float16 hcatL[64 * 296];
  const int t = threadIdx.x;
  const int i0 = blockIdx.x * 64;
  {
    const int mm = t >> 6, row = t & 63;
    const _Float16* pb = pacc + ((size_t)(mm * 8) * kN + (i0 + row)) * 72;
    constexpr size_t jstep = (size_t)kN * 72;
    float l = 0.f;
    #pragma unroll
    for (int s = 0; s < 8; s++) l += (float)pb[s * jstep + 66];
    float inv = 1.f / l;
    _Float16* hr = hcatL + row * 296 + mm * 66;
    #pragma unroll
    for (int c8 = 0; c8 < 9; c8++){
      float sv[8] = {0.f,0.f,0.f,0.f,0.f,0.f,0.f,0.f};
      #pragma unroll
      for (int s = 0; s < 8; s++){
        half8 hv = *(const half8*)&pb[s * jstep + c8 * 8];
        #pragma unroll
        for (int e = 0; e < 8; e++) sv[e] += (float)hv[e];
      }
      #pragma unroll
      for (int e = 0; e < 8; e++){
        int c = c8 * 8 + e;
        if (c < kDim){
          float vv = sv[e] * inv;
          vv = fmaxf(vv, kSlope * vv);
          hr[c] = (_Float16)vv;
        }
      }
    }
  }
  for (int z = t; z < 64 * 32; z += 256)
    hcatL[(z >> 5) * 296 + 264 + (z & 31)] = (_Float16)0.f;
  __syncthreads();
  const int w = t >> 6, n = t & 15;
  floatx4 acc[5];
  gemmN<9, 5>(hcatL + (w * 16 + n) * 296, B2tc, acc);
  epi0(acc, i0, Htoc, fo1c, fo2c, fmaxslot);
}

// ---------- fused: combine 16 out-split partials (vectorized) -> LDS -> gate/final GEMM ----------
template<int EPI>
__global__ __launch_bounds__(256) void combineO_gemm_k(
    const _Float16* __restrict__ pacc, const _Float16* __restrict__ Btc,
    float* __restrict__ uv, const float* __restrict__ hxp,
    _Float16* __restrict__ x2bp, float* __restrict__ outp)
{
  __shared__ __align__(16) _Float16 gbL[64 * 104];
  __shared__ float lds_l[64];
  const int t = threadIdx.x;
  const int i0 = blockIdx.x * 64;
  {
    const int row = t >> 2, part = t & 3;
    const _Float16* pb = pacc + (size_t)(i0 + row) * 72;
    constexpr size_t jstep = (size_t)kN * 72;
    const int nt_tiles = (part == 0) ? 3 : 2;
    int tiles[3] = { part, part + 4, 8 };
    float sums[3][8];
    #pragma unroll
    for (int ti = 0; ti < 3; ti++)
      #pragma unroll
      for (int e = 0; e < 8; e++) sums[ti][e] = 0.f;
    for (int s = 0; s < 16; s++){
      for (int ti = 0; ti < nt_tiles; ti++){
        half8 hv = *(const half8*)&pb[s * jstep + tiles[ti] * 8];
        #pragma unroll
        for (int e = 0; e < 8; e++) sums[ti][e] += (float)hv[e];
      }
    }
    if (part == 0) lds_l[row] = sums[2][2]; // col 66 = l
    __syncthreads();
    float inv = 1.f / lds_l[row];
    _Float16* gr = gbL + row * 104;
    for (int ti = 0; ti < nt_tiles; ti++){
      int T = tiles[ti];
      #pragma unroll
      for (int e = 0; e < 8; e++){
        int c = T * 8 + e;
        if (c < kDim){
          float vv = sums[ti][e] * inv;
          vv = fmaxf(vv, kSlope * vv);
          gr[c] = (_Float16)vv;
        } else if (c == 66) gr[66] = (_Float16)1.f;
        else if (c == 67) gr[67] = (_Float16)0.f;
      }
    }
    #pragma unroll
    for (int e = 0; e < 9; e++) gr[68 + part * 9 + e] = (_Float16)0.f;
  }
  __syncthreads();
  const int w = t >> 6, lane = t & 63, q = lane >> 4, n = lane & 15;
  const int ib = i0 + w * 16 + q * 4;
  if constexpr (EPI == 1){
    floatx4 acc[8];
    gemmN<3, 8>(gbL + (w * 16 + n) * 104, Btc, acc);
    #pragma unroll
    for (int nt = 0; nt < 8; nt++){
      int c = nt * 16 + n;
      #pragma unroll
      for (int r = 0; r < 4; r++){
        float v = 1.f / (1.f + __expf(-acc[nt][r]));
        if (c < 64) x2bp[(size_t)(ib + r) * 96 + 2 + c] = (_Float16)(v * hxp[(size_t)(ib + r) * kU + c]);
        else        uv[(size_t)(ib + r) * kU + (c - 64)] = v;
      }
    }
  } else {
    floatx4 acc[4];
    gemmN<3, 4>(gbL + (w * 16 + n) * 104, Btc, acc);
    #pragma unroll
    for (int nt = 0; nt < 4; nt++){
      int c = nt * 16 + n;
      #pragma unroll
      for (int r = 0; r < 4; r++){
        float cc2 = tanhf(acc[nt][r]);
        float u2 = uv[(size_t)(ib + r) * kU + c];
        outp[(size_t)(ib + r) * kU + c] = u2 * hxp[(size_t)(ib + r) * kU + c] + (1.f - u2) * cc2;
      }
    }
  }
}

extern "C" void kernel_launch(void* const* d_in, const int* in_sizes, int n_in,
                              void* d_out, int out_size, void* d_ws, size_t ws_size,
                              hipStream_t stream){
  const float* inputs  = (const float*)d_in[0];
  const float* hx      = (const float*)d_in[1];
  const int*   adj     = (const int*)d_in[2];
  const float* m1_W    = (const float*)d_in[3];
  const float* m1_a1   = (const float*)d_in[4];
  const float* m1_a2   = (const float*)d_in[5];
  const float* m1_Wout = (const float*)d_in[6];
  const float* m1_ao1  = (const float*)d_in[7];
  const float* m1_ao2  = (const float*)d_in[8];
  const float* m2_W    = (const float*)d_in[9];
  const float* m2_a1   = (const float*)d_in[10];
  const float* m2_a2   = (const float*)d_in[11];
  const float* m2_Wout = (const float*)d_in[12];
  const float* m2_ao1  = (const float*)d_in[13];
  const float* m2_ao2  = (const float*)d_in[14];
  const float* g1_W    = (const float*)d_in[15];
  const float* g1_b    = (const float*)d_in[16];
  const float* g2_W    = (const float*)d_in[17];
  const float* g2_b    = (const float*)d_in[18];
  float* out = (float*)d_out;

  char* ws = (char*)d_ws;
  size_t off = 0;
  auto alloc = [&](size_t bytes) -> void* {
    void* p = ws + off;
    off = (off + bytes + 255) & ~(size_t)255;
    return p;
  };
  unsigned long long* packed = (unsigned long long*)alloc((size_t)kN * 64 * 8);
  _Float16* x1b  = (_Float16*)alloc((size_t)kN * 96 * 2);
  _Float16* x2b  = (_Float16*)alloc((size_t)kN * 96 * 2);
  _Float16* Ht   = (_Float16*)alloc((size_t)4 * 80 * kN * 2);  // 80 rows: 68 real + 12 pad (uninit ok)
  _Float16* Hto  = (_Float16*)alloc((size_t)80 * kN * 2);
  float* f1   = (float*)alloc((size_t)4 * kN * 4);
  float* f2   = (float*)alloc((size_t)4 * kN * 4);
  float* fo1  = (float*)alloc((size_t)kN * 4);
  float* fo2  = (float*)alloc((size_t)kN * 4);
  unsigned int* fmaxbuf = (unsigned int*)alloc(64);
  float* u    = (float*)alloc((size_t)kN * kU * 4);
  _Float16* pacc = (_Float16*)alloc((size_t)32 * kN * 72 * 2);
  _Float16* B1t  = (_Float16*)alloc((size_t)4 * 80 * 96 * 2);
  _Float16* B1t2 = (_Float16*)alloc((size_t)4 * 80 * 96 * 2);
  _Float16* B2t  = (_Float16*)alloc((size_t)80 * 288 * 2);
  _Float16* B2t2 = (_Float16*)alloc((size_t)80 * 288 * 2);
  _Float16* Bgt  = (_Float16*)alloc((size_t)128 * 96 * 2);
  _Float16* Bft  = (_Float16*)alloc((size_t)64 * 96 * 2);
  (void)ws_size; (void)in_sizes; (void)n_in; (void)out_size;

  setup_k<<<16384 + 1024 + 12, 256, 0, stream>>>(adj, packed, inputs, hx, x1b, x2b,
      m1_W, m1_a1, m1_a2, m1_Wout, m1_ao1, m1_ao2,
      m2_W, m2_a1, m2_a2, m2_Wout, m2_ao1, m2_ao2,
      g1_W, g1_b, g2_W, g2_b,
      B1t, B1t2, B2t, B2t2, Bgt, Bft, fmaxbuf);

  // ---- subnet 1 ----
  gemm_ht_k<<<dim3(64, 4), 256, 0, stream>>>(x1b, B1t, Ht, f1, f2, fmaxbuf + 0);
  attn_mfma_k<4, 16><<<dim3(16, 4, 8), 256, 0, stream>>>(Ht, f1, f2, fmaxbuf + 0, packed, pacc);
  combineH_gemmO_k<<<64, 256, 0, stream>>>(pacc, B2t, Hto, fo1, fo2, fmaxbuf + 4);
  attn_mfma_k<2, 8><<<dim3(32, 1, 16), 256, 0, stream>>>(Hto, fo1, fo2, fmaxbuf + 4, packed, pacc);
  combineO_gemm_k<1><<<64, 256, 0, stream>>>(pacc, Bgt, u, hx, x2b, nullptr);

  // ---- subnet 2 ----
  gemm_ht_k<<<dim3(64, 4), 256, 0, stream>>>(x2b, B1t2, Ht, f1, f2, fmaxbuf + 5);
  attn_mfma_k<4, 16><<<dim3(16, 4, 8), 256, 0, stream>>>(Ht, f1, f2, fmaxbuf + 5, packed, pacc);
  combineH_gemmO_k<<<64, 256, 0, stream>>>(pacc, B2t2, Hto, fo1, fo2, fmaxbuf + 9);
  attn_mfma_k<2, 8><<<dim3(32, 1, 16), 256, 0, stream>>>(Hto, fo1, fo2, fmaxbuf + 9, packed, pacc);
  combineO_gemm_k<2><<<64, 256, 0, stream>>>(pacc, Bft, u, hx, nullptr, out);
}

// Round 9
// 339.712 us; speedup vs baseline: 1.0732x; 1.0732x over previous
//
#include <hip/hip_runtime.h>

constexpr int kN = 4096;
constexpr int kDim = 66;   // U + IN
constexpr int kU = 64;
constexpr float kAlpha = 0.2f;
constexpr float kSlope = 0.01f;
constexpr float kLog2e = 1.44269504f;

typedef _Float16 half8 __attribute__((ext_vector_type(8)));
typedef _Float16 half2t __attribute__((ext_vector_type(2)));
typedef float floatx4 __attribute__((ext_vector_type(4)));

__device__ inline unsigned int fkey(float f){ // monotone float->uint key for atomicMax
  unsigned int u = __float_as_uint(f);
  return (u & 0x80000000u) ? ~u : (u | 0x80000000u);
}
__device__ inline float funkey(unsigned int k){
  unsigned int u = (k & 0x80000000u) ? (k ^ 0x80000000u) : ~k;
  return __uint_as_float(u);
}

// ---------- merged setup: pack adjacency + build fp16 x1/x2 + all B matrices + fmax init ----------
__global__ void setup_k(const int* __restrict__ adj, unsigned long long* __restrict__ packed,
                        const float* __restrict__ in2, const float* __restrict__ hx,
                        _Float16* __restrict__ x1b, _Float16* __restrict__ x2b,
                        const float* __restrict__ m1W, const float* __restrict__ m1a1, const float* __restrict__ m1a2,
                        const float* __restrict__ m1Wo, const float* __restrict__ m1ao1, const float* __restrict__ m1ao2,
                        const float* __restrict__ m2W, const float* __restrict__ m2a1, const float* __restrict__ m2a2,
                        const float* __restrict__ m2Wo, const float* __restrict__ m2ao1, const float* __restrict__ m2ao2,
                        const float* __restrict__ g1W, const float* __restrict__ g1b,
                        const float* __restrict__ g2W, const float* __restrict__ g2b,
                        _Float16* __restrict__ B1t, _Float16* __restrict__ B1t2,
                        _Float16* __restrict__ B2t, _Float16* __restrict__ B2t2,
                        _Float16* __restrict__ Bgt, _Float16* __restrict__ Bft,
                        unsigned int* __restrict__ fmaxbuf){
  int bb = blockIdx.x, t = threadIdx.x;
  if (bb < 16384){
    int gid = bb * 256 + t;
    unsigned long long m = __ballot(adj[gid] != 0);
    if ((t & 63) == 0) packed[gid >> 6] = m;
    return;
  }
  if (bb < 16384 + 1024){
    int i = (bb - 16384) * 4 + (t >> 6);
    int c = t & 63;
    x1b[(size_t)i * 96 + 2 + c] = (_Float16)hx[(size_t)i * kU + c];
    if (c < 2){
      _Float16 xv = (_Float16)in2[i * 2 + c];
      x1b[(size_t)i * 96 + c] = xv;
      x2b[(size_t)i * 96 + c] = xv;
    }
    if (c < 30){ // zero pad cols 66..95 (ws is poisoned)
      x1b[(size_t)i * 96 + 66 + c] = (_Float16)0.f;
      x2b[(size_t)i * 96 + 66 + c] = (_Float16)0.f;
    }
    return;
  }
  int b = bb - (16384 + 1024);
  if (b < 8){
    int m = b & 3;
    const float* W  = (b < 4 ? m1W  : m2W)  + (size_t)m * kDim * kDim;
    const float* a1 = (b < 4 ? m1a1 : m2a1) + m * kDim;
    const float* a2 = (b < 4 ? m1a2 : m2a2) + m * kDim;
    _Float16* Bo = (b < 4 ? B1t : B1t2) + (size_t)m * 80 * 96;
    __shared__ float Ws[kDim * kDim];
    __shared__ float wa1s[kDim], wa2s[kDim];
    for (int z = t; z < kDim * kDim; z += 256) Ws[z] = W[z];
    __syncthreads();
    if (t < kDim){
      float s1 = 0.f, s2 = 0.f;
      for (int d = 0; d < kDim; d++){ float wv = Ws[t * kDim + d]; s1 += wv * a1[d]; s2 += wv * a2[d]; }
      wa1s[t] = s1; wa2s[t] = s2;
    }
    __syncthreads();
    for (int z = t; z < 80 * 96; z += 256){
      int nn = z / 96, k = z % 96;
      float val = 0.f;
      if (k < kDim){
        if (nn < kDim) val = Ws[k * kDim + nn];
        else if (nn == 66) val = wa1s[k];
        else if (nn == 67) val = wa2s[k];
      }
      Bo[z] = (_Float16)val;
    }
  } else if (b < 10){
    const float* Wo  = (b == 8 ? m1Wo  : m2Wo);
    const float* ao1 = (b == 8 ? m1ao1 : m2ao1);
    const float* ao2 = (b == 8 ? m1ao2 : m2ao2);
    _Float16* Bo = (b == 8 ? B2t : B2t2);
    __shared__ float wo1s[264], wo2s[264];
    for (int k = t; k < 264; k += 256){
      float s1 = 0.f, s2 = 0.f;
      for (int d = 0; d < kDim; d++){ float wv = Wo[(size_t)k * kDim + d]; s1 += wv * ao1[d]; s2 += wv * ao2[d]; }
      wo1s[k] = s1; wo2s[k] = s2;
    }
    __syncthreads();
    for (int z = t; z < 80 * 288; z += 256){
      int nn = z / 288, k = z % 288;
      float val = 0.f;
      if (k < 264){
        if (nn < kDim) val = Wo[(size_t)k * kDim + nn];
        else if (nn == 66) val = wo1s[k];
        else if (nn == 67) val = wo2s[k];
      }
      Bo[z] = (_Float16)val;
    }
  } else if (b == 10){
    for (int z = t; z < 128 * 96; z += 256){
      int nn = z / 96, k = z % 96;
      float val = 0.f;
      if (k < kDim) val = g1W[k * 128 + nn];
      else if (k == 66) val = g1b[nn];
      Bgt[z] = (_Float16)val;
    }
  } else {
    if (t < 16) fmaxbuf[t] = 0u;
    for (int z = t; z < 64 * 96; z += 256){
      int nn = z / 96, k = z % 96;
      float val = 0.f;
      if (k < kDim) val = g2W[k * 64 + nn];
      else if (k == 66) val = g2b[nn];
      Bft[z] = (_Float16)val;
    }
  }
}

// ---- generic MFMA GEMM core ----
template<int KSTEPS, int NT>
__device__ __forceinline__ void gemmN(const _Float16* __restrict__ Arow,
                                      const _Float16* __restrict__ Bt, floatx4* acc){
  const int lane = threadIdx.x & 63, q = lane >> 4, n = lane & 15;
  #pragma unroll
  for (int v = 0; v < NT; v++) acc[v] = (floatx4){0.f, 0.f, 0.f, 0.f};
  #pragma unroll
  for (int ks = 0; ks < KSTEPS; ks++){
    half8 af = *(const half8*)&Arow[ks * 32 + q * 8];
    #pragma unroll
    for (int nt = 0; nt < NT; nt++){
      half8 bf = *(const half8*)&Bt[(size_t)(nt * 16 + n) * (KSTEPS * 32) + ks * 32 + q * 8];
      acc[nt] = __builtin_amdgcn_mfma_f32_16x16x32_f16(af, bf, acc[nt], 0, 0, 0);
    }
  }
}

// ---- EPI0: store Ht (fp16 transposed + ones row 66 + zero row 67), f1/f2 (xlog2e), fmax ----
__device__ __forceinline__ void epi0(floatx4* acc, int i0, _Float16* __restrict__ Htc,
                                     float* __restrict__ f1c, float* __restrict__ f2c,
                                     unsigned* __restrict__ fmaxslot){
  const int t = threadIdx.x, w = t >> 6, lane = t & 63, q = lane >> 4, n = lane & 15;
  const int ib = i0 + w * 16 + q * 4;
  float lm = -3e38f;
  #pragma unroll
  for (int nt = 0; nt < 5; nt++){
    int c = nt * 16 + n;
    if (c < kDim){
      union { _Float16 h[4]; uint2 v; } pk;
      pk.h[0] = (_Float16)acc[nt][0]; pk.h[1] = (_Float16)acc[nt][1];
      pk.h[2] = (_Float16)acc[nt][2]; pk.h[3] = (_Float16)acc[nt][3];
      *(uint2*)&Htc[(size_t)c * kN + ib] = pk.v;
    } else if (c == 66){
      float4 fv; fv.x = acc[nt][0] * kLog2e; fv.y = acc[nt][1] * kLog2e;
      fv.z = acc[nt][2] * kLog2e; fv.w = acc[nt][3] * kLog2e;
      *(float4*)&f1c[ib] = fv;
      *(uint2*)&Htc[(size_t)66 * kN + ib] = make_uint2(0x3C003C00u, 0x3C003C00u);
    } else if (c == 67){
      float4 fv; fv.x = acc[nt][0] * kLog2e; fv.y = acc[nt][1] * kLog2e;
      fv.z = acc[nt][2] * kLog2e; fv.w = acc[nt][3] * kLog2e;
      *(float4*)&f2c[ib] = fv;
      lm = fmaxf(fmaxf(fv.x, fv.y), fmaxf(fv.z, fv.w));
      *(uint2*)&Htc[(size_t)67 * kN + ib] = make_uint2(0u, 0u);
    }
  }
  lm = fmaxf(lm, __shfl_xor(lm, 16));
  lm = fmaxf(lm, __shfl_xor(lm, 32));
  if (lane == 3) atomicMax(fmaxslot, fkey(lm));
}

// ---------- head transform GEMM ----------
__global__ __launch_bounds__(256) void gemm_ht_k(
    const _Float16* __restrict__ A, const _Float16* __restrict__ Bt,
    _Float16* __restrict__ Ht, float* __restrict__ f1, float* __restrict__ f2,
    unsigned int* __restrict__ fmaxp)
{
  const int m = blockIdx.y;
  const int i0 = blockIdx.x * 64;
  const int w = threadIdx.x >> 6, n = threadIdx.x & 15;
  floatx4 acc[5];
  gemmN<3, 5>(A + (size_t)(i0 + w * 16 + n) * 96, Bt + (size_t)m * 80 * 96, acc);
  epi0(acc, i0, Ht + (size_t)m * 80 * kN, f1 + (size_t)m * kN, f2 + (size_t)m * kN, fmaxp + m);
}

// ---------- LDS-staged MFMA attention, TPW A-tiles per wave (staged window reused 2x) ----------
// p_ij = exp2(lrelu(f1+f2)-S) = max(A1*B1_j, A2*B2_j); Ht row 66 = ones -> l_i; pacc stride 72
template<int TPW, int JSPLIT>
__global__ __launch_bounds__(256, 2) void attn_mfma_k(
    const _Float16* __restrict__ Ht, const float* __restrict__ f1,
    const float* __restrict__ f2, const unsigned int* __restrict__ fmaxu,
    const unsigned long long* __restrict__ packed,
    _Float16* __restrict__ paccb)
{
  constexpr int JR = kN / JSPLIT;
  constexpr int NCH = JR / 128;
  const int m = blockIdx.y, js = blockIdx.z;
  const int i0b = blockIdx.x * (TPW * 64);
  const int t = threadIdx.x;
  const int w = t >> 6, lane = t & 63, q = lane >> 4, n = lane & 15;
  const int wrb = i0b + w * (TPW * 16);
  const _Float16* Hg = Ht + (size_t)m * 80 * kN;
  const float* f2m = f2 + (size_t)m * kN;
  const float* f1m = f1 + (size_t)m * kN;
  const float fmx = funkey(fmaxu[m]);

  half2t a1p[TPW], a2p[TPW];
  const unsigned long long* prow[TPW];
  #pragma unroll
  for (int a = 0; a < TPW; a++){
    int i = wrb + a * 16 + n;
    float t0 = f1m[i] + fmx;
    float S = fmaxf(t0, kAlpha * t0);
    _Float16 A1 = (_Float16)__builtin_amdgcn_exp2f(t0 - S);
    _Float16 A2 = (_Float16)__builtin_amdgcn_exp2f(kAlpha * t0 - S);
    a1p[a] = (half2t){A1, A1};
    a2p[a] = (half2t){A2, A2};
    prow[a] = packed + (size_t)i * 64;
  }

  __shared__ __align__(16) _Float16 HtL[80 * 136];
  __shared__ __align__(16) _Float16 B1h[128], B2h[128];
  for (int z = t; z < 12 * 136; z += 256) HtL[68 * 136 + z] = (_Float16)0.f;

  floatx4 acc[TPW][5];
  #pragma unroll
  for (int a = 0; a < TPW; a++)
    #pragma unroll
    for (int v = 0; v < 5; v++) acc[a][v] = (floatx4){0.f, 0.f, 0.f, 0.f};

  const int jbase = js * JR;
  for (int ch = 0; ch < NCH; ch++){
    const int j0 = jbase + ch * 128;
    __syncthreads();
    for (int z = t; z < 68 * 16; z += 256){
      int row = z >> 4, c16 = z & 15;
      *(uint4*)&HtL[row * 136 + c16 * 8] = *(const uint4*)&Hg[(size_t)row * kN + j0 + c16 * 8];
    }
    if (t < 128){
      float v = f2m[j0 + t] - fmx;
      B1h[t] = (_Float16)__builtin_amdgcn_exp2f(v);
      B2h[t] = (_Float16)__builtin_amdgcn_exp2f(kAlpha * v);
    }
    __syncthreads();
    unsigned long long mw0[TPW], mw1[TPW];
    #pragma unroll
    for (int a = 0; a < TPW; a++){
      mw0[a] = prow[a][(j0 >> 6)];
      mw1[a] = prow[a][(j0 >> 6) + 1];
    }
    #pragma unroll
    for (int ks = 0; ks < 4; ks++){
      const unsigned shift = (ks & 1) * 32 + q * 8;
      const int jo = ks * 32 + q * 8;
      union { uint4 v; unsigned u[4]; } b1v, b2v;
      b1v.v = *(const uint4*)&B1h[jo];
      b2v.v = *(const uint4*)&B2h[jo];
      union { half8 s; unsigned u[4]; } af[TPW];
      #pragma unroll
      for (int a = 0; a < TPW; a++){
        unsigned bits = (unsigned)(((ks < 2 ? mw0[a] : mw1[a]) >> shift) & 0xffull);
        #pragma unroll
        for (int e = 0; e < 4; e++){
          half2t x1 = __builtin_bit_cast(half2t, b1v.u[e]);
          half2t x2 = __builtin_bit_cast(half2t, b2v.u[e]);
          half2t pm = __builtin_elementwise_max(x1 * a1p[a], x2 * a2p[a]);
          unsigned mmk = (((bits >> (2 * e)) & 1u) ? 0x0000FFFFu : 0u)
                       | (((bits >> (2 * e + 1)) & 1u) ? 0xFFFF0000u : 0u);
          af[a].u[e] = __builtin_bit_cast(unsigned, pm) & mmk;
        }
      }
      #pragma unroll
      for (int nt = 0; nt < 5; nt++){
        const half8 bf = *(const half8*)&HtL[(nt * 16 + n) * 136 + jo];
        #pragma unroll
        for (int a = 0; a < TPW; a++)
          acc[a][nt] = __builtin_amdgcn_mfma_f32_16x16x32_f16(af[a].s, bf, acc[a][nt], 0, 0, 0);
      }
    }
  }
  _Float16* pw = paccb + ((size_t)(m * JSPLIT + js) * kN + wrb) * 72;
  #pragma unroll
  for (int a = 0; a < TPW; a++){
    #pragma unroll
    for (int nt = 0; nt < 5; nt++){
      if (nt < 4 || n < 4){ // cols >= 68 unused
        #pragma unroll
        for (int r = 0; r < 4; r++)
          pw[(a * 16 + q * 4 + r) * 72 + nt * 16 + n] = (_Float16)acc[a][nt][r];
      }
    }
  }
}

// ---------- fused: combine 4-head/4-split partials -> LDS hcat -> out GEMM (K=288) -> epi0 ----------
__global__ __launch_bounds__(256) void combineH_gemmO_k(
    const _Float16* __restrict__ pacc, const _Float16* __restrict__ B2tc,
    _Float16* __restrict__ Htoc, float* __restrict__ fo1c, float* __restrict__ fo2c,
    unsigned int* __restrict__ fmaxslot)
{
  __shared__ __align__(16) _Float16 hcatL[64 * 296];
  const int t = threadIdx.x;
  const int i0 = blockIdx.x * 64;
  {
    const int mm = t >> 6, row = t & 63;
    const _Float16* pb = pacc + ((size_t)(mm * 4) * kN + (i0 + row)) * 72;
    constexpr size_t jstep = (size_t)kN * 72;
    float l = 0.f;
    #pragma unroll
    for (int s = 0; s < 4; s++) l += (float)pb[s * jstep + 66];
    float inv = 1.f / l;
    _Float16* hr = hcatL + row * 296 + mm * 66;
    #pragma unroll
    for (int c8 = 0; c8 < 9; c8++){
      float sv[8] = {0.f,0.f,0.f,0.f,0.f,0.f,0.f,0.f};
      #pragma unroll
      for (int s = 0; s < 4; s++){
        half8 hv = *(const half8*)&pb[s * jstep + c8 * 8];
        #pragma unroll
        for (int e = 0; e < 8; e++) sv[e] += (float)hv[e];
      }
      #pragma unroll
      for (int e = 0; e < 8; e++){
        int c = c8 * 8 + e;
        if (c < kDim){
          float vv = sv[e] * inv;
          vv = fmaxf(vv, kSlope * vv);
          hr[c] = (_Float16)vv;
        }
      }
    }
  }
  for (int z = t; z < 64 * 32; z += 256)
    hcatL[(z >> 5) * 296 + 264 + (z & 31)] = (_Float16)0.f;
  __syncthreads();
  const int w = t >> 6, n = t & 15;
  floatx4 acc[5];
  gemmN<9, 5>(hcatL + (w * 16 + n) * 296, B2tc, acc);
  epi0(acc, i0, Htoc, fo1c, fo2c, fmaxslot);
}

// ---------- fused: combine 16 out-split partials -> LDS -> gate(EPI=1)/final(EPI=2) GEMM ----------
template<int EPI>
__global__ __launch_bounds__(256) void combineO_gemm_k(
    const _Float16* __restrict__ pacc, const _Float16* __restrict__ Btc,
    float* __restrict__ uv, const float* __restrict__ hxp,
    _Float16* __restrict__ x2bp, float* __restrict__ outp)
{
  __shared__ __align__(16) _Float16 gbL[64 * 104];
  const int t = threadIdx.x;
  const int i0 = blockIdx.x * 64;
  {
    const int row = t >> 2, cg = t & 3;
    const _Float16* pb = pacc + (size_t)(i0 + row) * 72;
    constexpr size_t jstep = (size_t)kN * 72;
    float l = 0.f;
    #pragma unroll
    for (int s = 0; s < 16; s++) l += (float)pb[s * jstep + 66];
    float inv = 1.f / l;
    _Float16* gr = gbL + row * 104;
    for (int cc = 0; cc < 17; cc++){
      int c = cg * 17 + cc;
      if (c < kDim){
        float vv = 0.f;
        #pragma unroll
        for (int s = 0; s < 16; s++) vv += (float)pb[s * jstep + c];
        vv *= inv; vv = fmaxf(vv, kSlope * vv);
        gr[c] = (_Float16)vv;
      } else if (c == 66) gr[66] = (_Float16)1.f;
      else if (c == 67) gr[67] = (_Float16)0.f;
    }
    #pragma unroll
    for (int e = 0; e < 9; e++) gr[68 + cg * 9 + e] = (_Float16)0.f;
  }
  __syncthreads();
  const int w = t >> 6, lane = t & 63, q = lane >> 4, n = lane & 15;
  const int ib = i0 + w * 16 + q * 4;
  if constexpr (EPI == 1){
    floatx4 acc[8];
    gemmN<3, 8>(gbL + (w * 16 + n) * 104, Btc, acc);
    #pragma unroll
    for (int nt = 0; nt < 8; nt++){
      int c = nt * 16 + n;
      #pragma unroll
      for (int r = 0; r < 4; r++){
        float v = 1.f / (1.f + __expf(-acc[nt][r]));
        if (c < 64) x2bp[(size_t)(ib + r) * 96 + 2 + c] = (_Float16)(v * hxp[(size_t)(ib + r) * kU + c]);
        else        uv[(size_t)(ib + r) * kU + (c - 64)] = v;
      }
    }
  } else {
    floatx4 acc[4];
    gemmN<3, 4>(gbL + (w * 16 + n) * 104, Btc, acc);
    #pragma unroll
    for (int nt = 0; nt < 4; nt++){
      int c = nt * 16 + n;
      #pragma unroll
      for (int r = 0; r < 4; r++){
        float cc2 = tanhf(acc[nt][r]);
        float u2 = uv[(size_t)(ib + r) * kU + c];
        outp[(size_t)(ib + r) * kU + c] = u2 * hxp[(size_t)(ib + r) * kU + c] + (1.f - u2) * cc2;
      }
    }
  }
}

extern "C" void kernel_launch(void* const* d_in, const int* in_sizes, int n_in,
                              void* d_out, int out_size, void* d_ws, size_t ws_size,
                              hipStream_t stream){
  const float* inputs  = (const float*)d_in[0];
  const float* hx      = (const float*)d_in[1];
  const int*   adj     = (const int*)d_in[2];
  const float* m1_W    = (const float*)d_in[3];
  const float* m1_a1   = (const float*)d_in[4];
  const float* m1_a2   = (const float*)d_in[5];
  const float* m1_Wout = (const float*)d_in[6];
  const float* m1_ao1  = (const float*)d_in[7];
  const float* m1_ao2  = (const float*)d_in[8];
  const float* m2_W    = (const float*)d_in[9];
  const float* m2_a1   = (const float*)d_in[10];
  const float* m2_a2   = (const float*)d_in[11];
  const float* m2_Wout = (const float*)d_in[12];
  const float* m2_ao1  = (const float*)d_in[13];
  const float* m2_ao2  = (const float*)d_in[14];
  const float* g1_W    = (const float*)d_in[15];
  const float* g1_b    = (const float*)d_in[16];
  const float* g2_W    = (const float*)d_in[17];
  const float* g2_b    = (const float*)d_in[18];
  float* out = (float*)d_out;

  char* ws = (char*)d_ws;
  size_t off = 0;
  auto alloc = [&](size_t bytes) -> void* {
    void* p = ws + off;
    off = (off + bytes + 255) & ~(size_t)255;
    return p;
  };
  unsigned long long* packed = (unsigned long long*)alloc((size_t)kN * 64 * 8);
  _Float16* x1b  = (_Float16*)alloc((size_t)kN * 96 * 2);
  _Float16* x2b  = (_Float16*)alloc((size_t)kN * 96 * 2);
  _Float16* Ht   = (_Float16*)alloc((size_t)4 * 80 * kN * 2);
  _Float16* Hto  = (_Float16*)alloc((size_t)80 * kN * 2);
  float* f1   = (float*)alloc((size_t)4 * kN * 4);
  float* f2   = (float*)alloc((size_t)4 * kN * 4);
  float* fo1  = (float*)alloc((size_t)kN * 4);
  float* fo2  = (float*)alloc((size_t)kN * 4);
  unsigned int* fmaxbuf = (unsigned int*)alloc(64);
  float* u    = (float*)alloc((size_t)kN * kU * 4);
  _Float16* pacc = (_Float16*)alloc((size_t)16 * kN * 72 * 2);
  _Float16* B1t  = (_Float16*)alloc((size_t)4 * 80 * 96 * 2);
  _Float16* B1t2 = (_Float16*)alloc((size_t)4 * 80 * 96 * 2);
  _Float16* B2t  = (_Float16*)alloc((size_t)80 * 288 * 2);
  _Float16* B2t2 = (_Float16*)alloc((size_t)80 * 288 * 2);
  _Float16* Bgt  = (_Float16*)alloc((size_t)128 * 96 * 2);
  _Float16* Bft  = (_Float16*)alloc((size_t)64 * 96 * 2);
  (void)ws_size; (void)in_sizes; (void)n_in; (void)out_size;

  setup_k<<<16384 + 1024 + 12, 256, 0, stream>>>(adj, packed, inputs, hx, x1b, x2b,
      m1_W, m1_a1, m1_a2, m1_Wout, m1_ao1, m1_ao2,
      m2_W, m2_a1, m2_a2, m2_Wout, m2_ao1, m2_ao2,
      g1_W, g1_b, g2_W, g2_b,
      B1t, B1t2, B2t, B2t2, Bgt, Bft, fmaxbuf);

  // ---- subnet 1 ----
  gemm_ht_k<<<dim3(64, 4), 256, 0, stream>>>(x1b, B1t, Ht, f1, f2, fmaxbuf + 0);
  attn_mfma_k<2, 4><<<dim3(32, 4, 4), 256, 0, stream>>>(Ht, f1, f2, fmaxbuf + 0, packed, pacc);
  combineH_gemmO_k<<<64, 256, 0, stream>>>(pacc, B2t, Hto, fo1, fo2, fmaxbuf + 4);
  attn_mfma_k<2, 16><<<dim3(32, 1, 16), 256, 0, stream>>>(Hto, fo1, fo2, fmaxbuf + 4, packed, pacc);
  combineO_gemm_k<1><<<64, 256, 0, stream>>>(pacc, Bgt, u, hx, x2b, nullptr);

  // ---- subnet 2 ----
  gemm_ht_k<<<dim3(64, 4), 256, 0, stream>>>(x2b, B1t2, Ht, f1, f2, fmaxbuf + 5);
  attn_mfma_k<2, 4><<<dim3(32, 4, 4), 256, 0, stream>>>(Ht, f1, f2, fmaxbuf + 5, packed, pacc);
  combineH_gemmO_k<<<64, 256, 0, stream>>>(pacc, B2t2, Hto, fo1, fo2, fmaxbuf + 9);
  attn_mfma_k<2, 16><<<dim3(32, 1, 16), 256, 0, stream>>>(Hto, fo1, fo2, fmaxbuf + 9, packed, pacc);
  combineO_gemm_k<2><<<64, 256, 0, stream>>>(pacc, Bft, u, hx, nullptr, out);
}

// Round 10
// 329.044 us; speedup vs baseline: 1.1080x; 1.0324x over previous
//
#include <hip/hip_runtime.h>

constexpr int kN = 4096;
constexpr int kDim = 66;   // U + IN
constexpr int kU = 64;
constexpr float kAlpha = 0.2f;
constexpr float kSlope = 0.01f;
constexpr float kLog2e = 1.44269504f;

typedef _Float16 half8 __attribute__((ext_vector_type(8)));
typedef _Float16 half2t __attribute__((ext_vector_type(2)));
typedef float floatx4 __attribute__((ext_vector_type(4)));

__device__ inline unsigned int fkey(float f){ // monotone float->uint key for atomicMax
  unsigned int u = __float_as_uint(f);
  return (u & 0x80000000u) ? ~u : (u | 0x80000000u);
}
__device__ inline float funkey(unsigned int k){
  unsigned int u = (k & 0x80000000u) ? (k ^ 0x80000000u) : ~k;
  return __uint_as_float(u);
}

// ---------- merged setup: pack adjacency + build fp16 x1/x2 + all B matrices + fmax init ----------
__global__ void setup_k(const int* __restrict__ adj, unsigned long long* __restrict__ packed,
                        const float* __restrict__ in2, const float* __restrict__ hx,
                        _Float16* __restrict__ x1b, _Float16* __restrict__ x2b,
                        const float* __restrict__ m1W, const float* __restrict__ m1a1, const float* __restrict__ m1a2,
                        const float* __restrict__ m1Wo, const float* __restrict__ m1ao1, const float* __restrict__ m1ao2,
                        const float* __restrict__ m2W, const float* __restrict__ m2a1, const float* __restrict__ m2a2,
                        const float* __restrict__ m2Wo, const float* __restrict__ m2ao1, const float* __restrict__ m2ao2,
                        const float* __restrict__ g1W, const float* __restrict__ g1b,
                        const float* __restrict__ g2W, const float* __restrict__ g2b,
                        _Float16* __restrict__ B1t, _Float16* __restrict__ B1t2,
                        _Float16* __restrict__ B2t, _Float16* __restrict__ B2t2,
                        _Float16* __restrict__ Bgt, _Float16* __restrict__ Bft,
                        unsigned int* __restrict__ fmaxbuf){
  int bb = blockIdx.x, t = threadIdx.x;
  if (bb < 16384){
    int gid = bb * 256 + t;
    unsigned long long m = __ballot(adj[gid] != 0);
    if ((t & 63) == 0) packed[gid >> 6] = m;
    return;
  }
  if (bb < 16384 + 1024){
    int i = (bb - 16384) * 4 + (t >> 6);
    int c = t & 63;
    x1b[(size_t)i * 96 + 2 + c] = (_Float16)hx[(size_t)i * kU + c];
    if (c < 2){
      _Float16 xv = (_Float16)in2[i * 2 + c];
      x1b[(size_t)i * 96 + c] = xv;
      x2b[(size_t)i * 96 + c] = xv;
    }
    if (c < 30){ // zero pad cols 66..95 (ws is poisoned)
      x1b[(size_t)i * 96 + 66 + c] = (_Float16)0.f;
      x2b[(size_t)i * 96 + 66 + c] = (_Float16)0.f;
    }
    return;
  }
  int b = bb - (16384 + 1024);
  if (b < 8){
    int m = b & 3;
    const float* W  = (b < 4 ? m1W  : m2W)  + (size_t)m * kDim * kDim;
    const float* a1 = (b < 4 ? m1a1 : m2a1) + m * kDim;
    const float* a2 = (b < 4 ? m1a2 : m2a2) + m * kDim;
    _Float16* Bo = (b < 4 ? B1t : B1t2) + (size_t)m * 80 * 96;
    __shared__ float Ws[kDim * kDim];
    __shared__ float wa1s[kDim], wa2s[kDim];
    for (int z = t; z < kDim * kDim; z += 256) Ws[z] = W[z];
    __syncthreads();
    if (t < kDim){
      float s1 = 0.f, s2 = 0.f;
      for (int d = 0; d < kDim; d++){ float wv = Ws[t * kDim + d]; s1 += wv * a1[d]; s2 += wv * a2[d]; }
      wa1s[t] = s1; wa2s[t] = s2;
    }
    __syncthreads();
    for (int z = t; z < 80 * 96; z += 256){
      int nn = z / 96, k = z % 96;
      float val = 0.f;
      if (k < kDim){
        if (nn < kDim) val = Ws[k * kDim + nn];
        else if (nn == 66) val = wa1s[k];
        else if (nn == 67) val = wa2s[k];
      }
      Bo[z] = (_Float16)val;
    }
  } else if (b < 10){
    const float* Wo  = (b == 8 ? m1Wo  : m2Wo);
    const float* ao1 = (b == 8 ? m1ao1 : m2ao1);
    const float* ao2 = (b == 8 ? m1ao2 : m2ao2);
    _Float16* Bo = (b == 8 ? B2t : B2t2);
    __shared__ float wo1s[264], wo2s[264];
    for (int k = t; k < 264; k += 256){
      float s1 = 0.f, s2 = 0.f;
      for (int d = 0; d < kDim; d++){ float wv = Wo[(size_t)k * kDim + d]; s1 += wv * ao1[d]; s2 += wv * ao2[d]; }
      wo1s[k] = s1; wo2s[k] = s2;
    }
    __syncthreads();
    for (int z = t; z < 80 * 288; z += 256){
      int nn = z / 288, k = z % 288;
      float val = 0.f;
      if (k < 264){
        if (nn < kDim) val = Wo[(size_t)k * kDim + nn];
        else if (nn == 66) val = wo1s[k];
        else if (nn == 67) val = wo2s[k];
      }
      Bo[z] = (_Float16)val;
    }
  } else if (b == 10){
    for (int z = t; z < 128 * 96; z += 256){
      int nn = z / 96, k = z % 96;
      float val = 0.f;
      if (k < kDim) val = g1W[k * 128 + nn];
      else if (k == 66) val = g1b[nn];
      Bgt[z] = (_Float16)val;
    }
  } else {
    if (t < 16) fmaxbuf[t] = 0u;
    for (int z = t; z < 64 * 96; z += 256){
      int nn = z / 96, k = z % 96;
      float val = 0.f;
      if (k < kDim) val = g2W[k * 64 + nn];
      else if (k == 66) val = g2b[nn];
      Bft[z] = (_Float16)val;
    }
  }
}

// ---- generic MFMA GEMM core ----
template<int KSTEPS, int NT>
__device__ __forceinline__ void gemmN(const _Float16* __restrict__ Arow,
                                      const _Float16* __restrict__ Bt, floatx4* acc){
  const int lane = threadIdx.x & 63, q = lane >> 4, n = lane & 15;
  #pragma unroll
  for (int v = 0; v < NT; v++) acc[v] = (floatx4){0.f, 0.f, 0.f, 0.f};
  #pragma unroll
  for (int ks = 0; ks < KSTEPS; ks++){
    half8 af = *(const half8*)&Arow[ks * 32 + q * 8];
    #pragma unroll
    for (int nt = 0; nt < NT; nt++){
      half8 bf = *(const half8*)&Bt[(size_t)(nt * 16 + n) * (KSTEPS * 32) + ks * 32 + q * 8];
      acc[nt] = __builtin_amdgcn_mfma_f32_16x16x32_f16(af, bf, acc[nt], 0, 0, 0);
    }
  }
}

// ---- EPI0: store Ht (fp16 transposed + ones row 66 + zero row 67), f1/f2 (xlog2e), fmax ----
__device__ __forceinline__ void epi0(floatx4* acc, int i0, _Float16* __restrict__ Htc,
                                     float* __restrict__ f1c, float* __restrict__ f2c,
                                     unsigned* __restrict__ fmaxslot){
  const int t = threadIdx.x, w = t >> 6, lane = t & 63, q = lane >> 4, n = lane & 15;
  const int ib = i0 + w * 16 + q * 4;
  float lm = -3e38f;
  #pragma unroll
  for (int nt = 0; nt < 5; nt++){
    int c = nt * 16 + n;
    if (c < kDim){
      union { _Float16 h[4]; uint2 v; } pk;
      pk.h[0] = (_Float16)acc[nt][0]; pk.h[1] = (_Float16)acc[nt][1];
      pk.h[2] = (_Float16)acc[nt][2]; pk.h[3] = (_Float16)acc[nt][3];
      *(uint2*)&Htc[(size_t)c * kN + ib] = pk.v;
    } else if (c == 66){
      float4 fv; fv.x = acc[nt][0] * kLog2e; fv.y = acc[nt][1] * kLog2e;
      fv.z = acc[nt][2] * kLog2e; fv.w = acc[nt][3] * kLog2e;
      *(float4*)&f1c[ib] = fv;
      *(uint2*)&Htc[(size_t)66 * kN + ib] = make_uint2(0x3C003C00u, 0x3C003C00u);
    } else if (c == 67){
      float4 fv; fv.x = acc[nt][0] * kLog2e; fv.y = acc[nt][1] * kLog2e;
      fv.z = acc[nt][2] * kLog2e; fv.w = acc[nt][3] * kLog2e;
      *(float4*)&f2c[ib] = fv;
      lm = fmaxf(fmaxf(fv.x, fv.y), fmaxf(fv.z, fv.w));
      *(uint2*)&Htc[(size_t)67 * kN + ib] = make_uint2(0u, 0u);
    }
  }
  lm = fmaxf(lm, __shfl_xor(lm, 16));
  lm = fmaxf(lm, __shfl_xor(lm, 32));
  if (lane == 3) atomicMax(fmaxslot, fkey(lm));
}

// ---------- head transform GEMM ----------
__global__ __launch_bounds__(256) void gemm_ht_k(
    const _Float16* __restrict__ A, const _Float16* __restrict__ Bt,
    _Float16* __restrict__ Ht, float* __restrict__ f1, float* __restrict__ f2,
    unsigned int* __restrict__ fmaxp)
{
  const int m = blockIdx.y;
  const int i0 = blockIdx.x * 64;
  const int w = threadIdx.x >> 6, n = threadIdx.x & 15;
  floatx4 acc[5];
  gemmN<3, 5>(A + (size_t)(i0 + w * 16 + n) * 96, Bt + (size_t)m * 80 * 96, acc);
  epi0(acc, i0, Ht + (size_t)m * 80 * kN, f1 + (size_t)m * kN, f2 + (size_t)m * kN, fmaxp + m);
}

// ---------- LDS-staged MFMA attention, TPW A-tiles per wave, 4 blocks/CU ----------
// p_ij = exp2(lrelu(f1+f2)-S) = max(A1*B1_j, A2*B2_j); Ht row 66 = ones -> l_i; pacc stride 72
template<int TPW, int JSPLIT>
__global__ __launch_bounds__(256, 4) void attn_mfma_k(
    const _Float16* __restrict__ Ht, const float* __restrict__ f1,
    const float* __restrict__ f2, const unsigned int* __restrict__ fmaxu,
    const unsigned long long* __restrict__ packed,
    _Float16* __restrict__ paccb)
{
  constexpr int JR = kN / JSPLIT;
  constexpr int NCH = JR / 128;
  const int m = blockIdx.y, js = blockIdx.z;
  const int i0b = blockIdx.x * (TPW * 64);
  const int t = threadIdx.x;
  const int w = t >> 6, lane = t & 63, q = lane >> 4, n = lane & 15;
  const int wrb = i0b + w * (TPW * 16);
  const _Float16* Hg = Ht + (size_t)m * 80 * kN;
  const float* f2m = f2 + (size_t)m * kN;
  const float* f1m = f1 + (size_t)m * kN;
  const float fmx = funkey(fmaxu[m]);

  half2t a1p[TPW], a2p[TPW];
  const unsigned long long* prow[TPW];
  #pragma unroll
  for (int a = 0; a < TPW; a++){
    int i = wrb + a * 16 + n;
    float t0 = f1m[i] + fmx;
    float S = fmaxf(t0, kAlpha * t0);
    _Float16 A1 = (_Float16)__builtin_amdgcn_exp2f(t0 - S);
    _Float16 A2 = (_Float16)__builtin_amdgcn_exp2f(kAlpha * t0 - S);
    a1p[a] = (half2t){A1, A1};
    a2p[a] = (half2t){A2, A2};
    prow[a] = packed + (size_t)i * 64;
  }

  __shared__ __align__(16) _Float16 HtL[80 * 136];
  __shared__ __align__(16) _Float16 B1h[128], B2h[128];
  for (int z = t; z < 12 * 136; z += 256) HtL[68 * 136 + z] = (_Float16)0.f;

  floatx4 acc[TPW][5];
  #pragma unroll
  for (int a = 0; a < TPW; a++)
    #pragma unroll
    for (int v = 0; v < 5; v++) acc[a][v] = (floatx4){0.f, 0.f, 0.f, 0.f};

  const int jbase = js * JR;
  for (int ch = 0; ch < NCH; ch++){
    const int j0 = jbase + ch * 128;
    __syncthreads();
    for (int z = t; z < 68 * 16; z += 256){
      int row = z >> 4, c16 = z & 15;
      *(uint4*)&HtL[row * 136 + c16 * 8] = *(const uint4*)&Hg[(size_t)row * kN + j0 + c16 * 8];
    }
    if (t < 128){
      float v = f2m[j0 + t] - fmx;
      B1h[t] = (_Float16)__builtin_amdgcn_exp2f(v);
      B2h[t] = (_Float16)__builtin_amdgcn_exp2f(kAlpha * v);
    }
    __syncthreads();
    unsigned long long mw0[TPW], mw1[TPW];
    #pragma unroll
    for (int a = 0; a < TPW; a++){
      mw0[a] = prow[a][(j0 >> 6)];
      mw1[a] = prow[a][(j0 >> 6) + 1];
    }
    #pragma unroll
    for (int ks = 0; ks < 4; ks++){
      const unsigned shift = (ks & 1) * 32 + q * 8;
      const int jo = ks * 32 + q * 8;
      union { uint4 v; unsigned u[4]; } b1v, b2v;
      b1v.v = *(const uint4*)&B1h[jo];
      b2v.v = *(const uint4*)&B2h[jo];
      union { half8 s; unsigned u[4]; } af[TPW];
      #pragma unroll
      for (int a = 0; a < TPW; a++){
        unsigned bits = (unsigned)(((ks < 2 ? mw0[a] : mw1[a]) >> shift) & 0xffull);
        #pragma unroll
        for (int e = 0; e < 4; e++){
          half2t x1 = __builtin_bit_cast(half2t, b1v.u[e]);
          half2t x2 = __builtin_bit_cast(half2t, b2v.u[e]);
          half2t pm = __builtin_elementwise_max(x1 * a1p[a], x2 * a2p[a]);
          unsigned mmk = (((bits >> (2 * e)) & 1u) ? 0x0000FFFFu : 0u)
                       | (((bits >> (2 * e + 1)) & 1u) ? 0xFFFF0000u : 0u);
          af[a].u[e] = __builtin_bit_cast(unsigned, pm) & mmk;
        }
      }
      #pragma unroll
      for (int nt = 0; nt < 5; nt++){
        const half8 bf = *(const half8*)&HtL[(nt * 16 + n) * 136 + jo];
        #pragma unroll
        for (int a = 0; a < TPW; a++)
          acc[a][nt] = __builtin_amdgcn_mfma_f32_16x16x32_f16(af[a].s, bf, acc[a][nt], 0, 0, 0);
      }
    }
  }
  _Float16* pw = paccb + ((size_t)(m * JSPLIT + js) * kN + wrb) * 72;
  #pragma unroll
  for (int a = 0; a < TPW; a++){
    #pragma unroll
    for (int nt = 0; nt < 5; nt++){
      if (nt < 4 || n < 4){ // cols >= 68 unused
        #pragma unroll
        for (int r = 0; r < 4; r++)
          pw[(a * 16 + q * 4 + r) * 72 + nt * 16 + n] = (_Float16)acc[a][nt][r];
      }
    }
  }
}

// ---------- fused: combine 4-head/8-split partials -> LDS hcat -> out GEMM (K=288) -> epi0 ----------
__global__ __launch_bounds__(256) void combineH_gemmO_k(
    const _Float16* __restrict__ pacc, const _Float16* __restrict__ B2tc,
    _Float16* __restrict__ Htoc, float* __restrict__ fo1c, float* __restrict__ fo2c,
    unsigned int* __restrict__ fmaxslot)
{
  __shared__ __align__(16) _Float16 hcatL[64 * 296];
  const int t = threadIdx.x;
  const int i0 = blockIdx.x * 64;
  {
    const int mm = t >> 6, row = t & 63;
    const _Float16* pb = pacc + ((size_t)(mm * 8) * kN + (i0 + row)) * 72;
    constexpr size_t jstep = (size_t)kN * 72;
    float l = 0.f;
    #pragma unroll
    for (int s = 0; s < 8; s++) l += (float)pb[s * jstep + 66];
    float inv = 1.f / l;
    _Float16* hr = hcatL + row * 296 + mm * 66;
    #pragma unroll
    for (int c8 = 0; c8 < 9; c8++){
      float sv[8] = {0.f,0.f,0.f,0.f,0.f,0.f,0.f,0.f};
      #pragma unroll
      for (int s = 0; s < 8; s++){
        half8 hv = *(const half8*)&pb[s * jstep + c8 * 8];
        #pragma unroll
        for (int e = 0; e < 8; e++) sv[e] += (float)hv[e];
      }
      #pragma unroll
      for (int e = 0; e < 8; e++){
        int c = c8 * 8 + e;
        if (c < kDim){
          float vv = sv[e] * inv;
          vv = fmaxf(vv, kSlope * vv);
          hr[c] = (_Float16)vv;
        }
      }
    }
  }
  for (int z = t; z < 64 * 32; z += 256)
    hcatL[(z >> 5) * 296 + 264 + (z & 31)] = (_Float16)0.f;
  __syncthreads();
  const int w = t >> 6, n = t & 15;
  floatx4 acc[5];
  gemmN<9, 5>(hcatL + (w * 16 + n) * 296, B2tc, acc);
  epi0(acc, i0, Htoc, fo1c, fo2c, fmaxslot);
}

// ---------- fused: combine 16 out-split partials -> LDS -> gate(EPI=1)/final(EPI=2) GEMM ----------
template<int EPI>
__global__ __launch_bounds__(256) void combineO_gemm_k(
    const _Float16* __restrict__ pacc, const _Float16* __restrict__ Btc,
    float* __restrict__ uv, const float* __restrict__ hxp,
    _Float16* __restrict__ x2bp, float* __restrict__ outp)
{
  __shared__ __align__(16) _Float16 gbL[64 * 104];
  const int t = threadIdx.x;
  const int i0 = blockIdx.x * 64;
  {
    const int row = t >> 2, cg = t & 3;
    const _Float16* pb = pacc + (size_t)(i0 + row) * 72;
    constexpr size_t jstep = (size_t)kN * 72;
    float l = 0.f;
    #pragma unroll
    for (int s = 0; s < 16; s++) l += (float)pb[s * jstep + 66];
    float inv = 1.f / l;
    _Float16* gr = gbL + row * 104;
    for (int cc = 0; cc < 17; cc++){
      int c = cg * 17 + cc;
      if (c < kDim){
        float vv = 0.f;
        #pragma unroll
        for (int s = 0; s < 16; s++) vv += (float)pb[s * jstep + c];
        vv *= inv; vv = fmaxf(vv, kSlope * vv);
        gr[c] = (_Float16)vv;
      } else if (c == 66) gr[66] = (_Float16)1.f;
      else if (c == 67) gr[67] = (_Float16)0.f;
    }
    #pragma unroll
    for (int e = 0; e < 9; e++) gr[68 + cg * 9 + e] = (_Float16)0.f;
  }
  __syncthreads();
  const int w = t >> 6, lane = t & 63, q = lane >> 4, n = lane & 15;
  const int ib = i0 + w * 16 + q * 4;
  if constexpr (EPI == 1){
    floatx4 acc[8];
    gemmN<3, 8>(gbL + (w * 16 + n) * 104, Btc, acc);
    #pragma unroll
    for (int nt = 0; nt < 8; nt++){
      int c = nt * 16 + n;
      #pragma unroll
      for (int r = 0; r < 4; r++){
        float v = 1.f / (1.f + __expf(-acc[nt][r]));
        if (c < 64) x2bp[(size_t)(ib + r) * 96 + 2 + c] = (_Float16)(v * hxp[(size_t)(ib + r) * kU + c]);
        else        uv[(size_t)(ib + r) * kU + (c - 64)] = v;
      }
    }
  } else {
    floatx4 acc[4];
    gemmN<3, 4>(gbL + (w * 16 + n) * 104, Btc, acc);
    #pragma unroll
    for (int nt = 0; nt < 4; nt++){
      int c = nt * 16 + n;
      #pragma unroll
      for (int r = 0; r < 4; r++){
        float cc2 = tanhf(acc[nt][r]);
        float u2 = uv[(size_t)(ib + r) * kU + c];
        outp[(size_t)(ib + r) * kU + c] = u2 * hxp[(size_t)(ib + r) * kU + c] + (1.f - u2) * cc2;
      }
    }
  }
}

extern "C" void kernel_launch(void* const* d_in, const int* in_sizes, int n_in,
                              void* d_out, int out_size, void* d_ws, size_t ws_size,
                              hipStream_t stream){
  const float* inputs  = (const float*)d_in[0];
  const float* hx      = (const float*)d_in[1];
  const int*   adj     = (const int*)d_in[2];
  const float* m1_W    = (const float*)d_in[3];
  const float* m1_a1   = (const float*)d_in[4];
  const float* m1_a2   = (const float*)d_in[5];
  const float* m1_Wout = (const float*)d_in[6];
  const float* m1_ao1  = (const float*)d_in[7];
  const float* m1_ao2  = (const float*)d_in[8];
  const float* m2_W    = (const float*)d_in[9];
  const float* m2_a1   = (const float*)d_in[10];
  const float* m2_a2   = (const float*)d_in[11];
  const float* m2_Wout = (const float*)d_in[12];
  const float* m2_ao1  = (const float*)d_in[13];
  const float* m2_ao2  = (const float*)d_in[14];
  const float* g1_W    = (const float*)d_in[15];
  const float* g1_b    = (const float*)d_in[16];
  const float* g2_W    = (const float*)d_in[17];
  const float* g2_b    = (const float*)d_in[18];
  float* out = (float*)d_out;

  char* ws = (char*)d_ws;
  size_t off = 0;
  auto alloc = [&](size_t bytes) -> void* {
    void* p = ws + off;
    off = (off + bytes + 255) & ~(size_t)255;
    return p;
  };
  unsigned long long* packed = (unsigned long long*)alloc((size_t)kN * 64 * 8);
  _Float16* x1b  = (_Float16*)alloc((size_t)kN * 96 * 2);
  _Float16* x2b  = (_Float16*)alloc((size_t)kN * 96 * 2);
  _Float16* Ht   = (_Float16*)alloc((size_t)4 * 80 * kN * 2);
  _Float16* Hto  = (_Float16*)alloc((size_t)80 * kN * 2);
  float* f1   = (float*)alloc((size_t)4 * kN * 4);
  float* f2   = (float*)alloc((size_t)4 * kN * 4);
  float* fo1  = (float*)alloc((size_t)kN * 4);
  float* fo2  = (float*)alloc((size_t)kN * 4);
  unsigned int* fmaxbuf = (unsigned int*)alloc(64);
  float* u    = (float*)alloc((size_t)kN * kU * 4);
  _Float16* pacc = (_Float16*)alloc((size_t)32 * kN * 72 * 2); // 32 slices (head JSPLIT=8 x 4 heads)
  _Float16* B1t  = (_Float16*)alloc((size_t)4 * 80 * 96 * 2);
  _Float16* B1t2 = (_Float16*)alloc((size_t)4 * 80 * 96 * 2);
  _Float16* B2t  = (_Float16*)alloc((size_t)80 * 288 * 2);
  _Float16* B2t2 = (_Float16*)alloc((size_t)80 * 288 * 2);
  _Float16* Bgt  = (_Float16*)alloc((size_t)128 * 96 * 2);
  _Float16* Bft  = (_Float16*)alloc((size_t)64 * 96 * 2);
  (void)ws_size; (void)in_sizes; (void)n_in; (void)out_size;

  setup_k<<<16384 + 1024 + 12, 256, 0, stream>>>(adj, packed, inputs, hx, x1b, x2b,
      m1_W, m1_a1, m1_a2, m1_Wout, m1_ao1, m1_ao2,
      m2_W, m2_a1, m2_a2, m2_Wout, m2_ao1, m2_ao2,
      g1_W, g1_b, g2_W, g2_b,
      B1t, B1t2, B2t, B2t2, Bgt, Bft, fmaxbuf);

  // ---- subnet 1 ----
  gemm_ht_k<<<dim3(64, 4), 256, 0, stream>>>(x1b, B1t, Ht, f1, f2, fmaxbuf + 0);
  attn_mfma_k<2, 8><<<dim3(32, 4, 8), 256, 0, stream>>>(Ht, f1, f2, fmaxbuf + 0, packed, pacc);
  combineH_gemmO_k<<<64, 256, 0, stream>>>(pacc, B2t, Hto, fo1, fo2, fmaxbuf + 4);
  attn_mfma_k<1, 16><<<dim3(64, 1, 16), 256, 0, stream>>>(Hto, fo1, fo2, fmaxbuf + 4, packed, pacc);
  combineO_gemm_k<1><<<64, 256, 0, stream>>>(pacc, Bgt, u, hx, x2b, nullptr);

  // ---- subnet 2 ----
  gemm_ht_k<<<dim3(64, 4), 256, 0, stream>>>(x2b, B1t2, Ht, f1, f2, fmaxbuf + 5);
  attn_mfma_k<2, 8><<<dim3(32, 4, 8), 256, 0, stream>>>(Ht, f1, f2, fmaxbuf + 5, packed, pacc);
  combineH_gemmO_k<<<64, 256, 0, stream>>>(pacc, B2t2, Hto, fo1, fo2, fmaxbuf + 9);
  attn_mfma_k<1, 16><<<dim3(64, 1, 16), 256, 0, stream>>>(Hto, fo1, fo2, fmaxbuf + 9, packed, pacc);
  combineO_gemm_k<2><<<64, 256, 0, stream>>>(pacc, Bft, u, hx, nullptr, out);
}